// Round 2
// baseline (199.983 us; speedup 1.0000x reference)
//
#include <hip/hip_runtime.h>
#include <hip/hip_bf16.h>

// GraphSAGE 2-layer: N=50000, D=128, DEG=16.
// R2: gather fused into GEMM A-staging (no hcat round-trip); 3 launches total.
typedef __attribute__((ext_vector_type(8))) short short8;
typedef __attribute__((ext_vector_type(4))) float f32x4;

#define N_NODES 50000
#define D 128
#define DEG 16
#define K2 256   // 2*D
#define BM 64    // rows per block

static __device__ __forceinline__ unsigned short f2b(float f) {
    union { float f; unsigned int u; } v; v.f = f;
    return (unsigned short)((v.u + 0x7fffu + ((v.u >> 16) & 1u)) >> 16);
}
static __device__ __forceinline__ float b2f(unsigned short u) {
    union { unsigned int u; float f; } v; v.u = ((unsigned int)u) << 16;
    return v.f;
}

// ---- prep: x -> bf16 ; W1,W2 -> bf16 transposed (n-major) ----
__global__ void prep(const float* __restrict__ x, unsigned short* __restrict__ xb,
                     const float* __restrict__ W1, const float* __restrict__ W2,
                     unsigned short* __restrict__ Wt1, unsigned short* __restrict__ Wt2) {
    int b = blockIdx.x;
    if (b < 128) {
        int i = b * 256 + threadIdx.x;       // i in [0, K2*D)
        int k = i / D, n = i % D;
        Wt1[n * K2 + k] = f2b(W1[i]);
        Wt2[n * K2 + k] = f2b(W2[i]);
    } else {
        int i = ((b - 128) * 256 + threadIdx.x) * 4;
        if (i < N_NODES * D) {
            float4 v = *(const float4*)(x + i);
            ushort4 o;
            o.x = f2b(v.x); o.y = f2b(v.y); o.z = f2b(v.z); o.w = f2b(v.w);
            *(ushort4*)(xb + i) = o;
        }
    }
}

// ---- fused layer: out = relu( [feat | mean_nbr(feat)] @ W + b ) ----
template <int OUT_BF16>
__global__ __launch_bounds__(256)
void sage_layer(const unsigned short* __restrict__ feat,  // N x D bf16
                const int* __restrict__ nbr,              // N x DEG
                const unsigned short* __restrict__ wt,    // D x K2 bf16 (n-major)
                const float* __restrict__ bias,           // D f32
                void* __restrict__ out)
{
    __shared__ __align__(16) unsigned short Hl[BM * 264];  // A tile, row stride 264
    __shared__ int Nl[BM * DEG];                           // neighbor ids for 64 rows
    const int tid  = threadIdx.x;
    const int row0 = blockIdx.x * BM;

    // stage neighbor indices (1024 ints)
    {
        int g = row0 * DEG + tid * 4;
        int gmax = N_NODES * DEG - 4;
        if (g > gmax) g = gmax;              // clamp (tail block); unused rows ignored
        *(int4*)(Nl + tid * 4) = *(const int4*)(nbr + g);
    }
    __syncthreads();

    // ---- gather phase: thread = (row r = tid>>2, quarter q = tid&3), 32 dims each
    {
        const int r = tid >> 2;
        const int q = tid & 3;
        int grow = row0 + r;
        if (grow >= N_NODES) grow = N_NODES - 1;
        const unsigned short* sp = feat + (size_t)grow * D + q * 32;
        short8 s0 = *(const short8*)(sp);
        short8 s1 = *(const short8*)(sp + 8);
        short8 s2 = *(const short8*)(sp + 16);
        short8 s3 = *(const short8*)(sp + 24);

        float am[32];
        #pragma unroll
        for (int i = 0; i < 32; ++i) am[i] = 0.f;
        #pragma unroll
        for (int j = 0; j < DEG; ++j) {
            int nid = Nl[r * DEG + j];
            const unsigned short* p = feat + (size_t)nid * D + q * 32;
            short8 v0 = *(const short8*)(p);
            short8 v1 = *(const short8*)(p + 8);
            short8 v2 = *(const short8*)(p + 16);
            short8 v3 = *(const short8*)(p + 24);
            #pragma unroll
            for (int i = 0; i < 8; ++i) {
                am[i]      += b2f((unsigned short)v0[i]);
                am[8 + i]  += b2f((unsigned short)v1[i]);
                am[16 + i] += b2f((unsigned short)v2[i]);
                am[24 + i] += b2f((unsigned short)v3[i]);
            }
        }
        unsigned short* hr = Hl + r * 264;
        *(short8*)(hr + q * 32)      = s0;
        *(short8*)(hr + q * 32 + 8)  = s1;
        *(short8*)(hr + q * 32 + 16) = s2;
        *(short8*)(hr + q * 32 + 24) = s3;
        #pragma unroll
        for (int c = 0; c < 4; ++c) {
            short8 m;
            #pragma unroll
            for (int i = 0; i < 8; ++i) m[i] = (short)f2b(am[c * 8 + i] * 0.0625f);
            *(short8*)(hr + D + q * 32 + c * 8) = m;
        }
    }

    // ---- B fragments (loaded post-gather to keep VGPR live ranges disjoint)
    const int lane = tid & 63;
    const int w    = tid >> 6;
    const int quad = lane >> 4;
    const int l16  = lane & 15;
    const int n_base = w * 32;
    short8 bfrag[8][2];
    #pragma unroll
    for (int kk = 0; kk < 8; ++kk)
        #pragma unroll
        for (int ct = 0; ct < 2; ++ct)
            bfrag[kk][ct] = *(const short8*)(wt + (n_base + ct * 16 + l16) * K2 + kk * 32 + quad * 8);

    __syncthreads();

    // ---- MFMA phase
    f32x4 acc[4][2];
    #pragma unroll
    for (int rt = 0; rt < 4; ++rt)
        #pragma unroll
        for (int ct = 0; ct < 2; ++ct)
            acc[rt][ct] = (f32x4){0.f, 0.f, 0.f, 0.f};

    #pragma unroll
    for (int kk = 0; kk < 8; ++kk) {
        short8 afrag[4];
        #pragma unroll
        for (int rt = 0; rt < 4; ++rt)
            afrag[rt] = *(const short8*)(&Hl[(rt * 16 + l16) * 264 + kk * 32 + quad * 8]);
        #pragma unroll
        for (int rt = 0; rt < 4; ++rt)
            #pragma unroll
            for (int ct = 0; ct < 2; ++ct)
                acc[rt][ct] = __builtin_amdgcn_mfma_f32_16x16x32_bf16(
                    afrag[rt], bfrag[kk][ct], acc[rt][ct], 0, 0, 0);
    }

    // ---- epilogue: C[row0 + rt*16 + quad*4 + r][n_base + ct*16 + l16]
    float bv0 = bias[n_base + l16];
    float bv1 = bias[n_base + 16 + l16];
    #pragma unroll
    for (int rt = 0; rt < 4; ++rt) {
        int grow_base = row0 + rt * 16 + quad * 4;
        #pragma unroll
        for (int r = 0; r < 4; ++r) {
            int grow = grow_base + r;
            if (grow >= N_NODES) continue;
            #pragma unroll
            for (int ct = 0; ct < 2; ++ct) {
                float v = acc[rt][ct][r] + (ct ? bv1 : bv0);
                v = v > 0.f ? v : 0.f;
                int col = n_base + ct * 16 + l16;
                if (OUT_BF16)
                    ((unsigned short*)out)[grow * D + col] = f2b(v);
                else
                    ((float*)out)[grow * D + col] = v;
            }
        }
    }
}

extern "C" void kernel_launch(void* const* d_in, const int* in_sizes, int n_in,
                              void* d_out, int out_size, void* d_ws, size_t ws_size,
                              hipStream_t stream) {
    const float* x  = (const float*)d_in[0];
    const int*   nb = (const int*)d_in[1];
    const float* W1 = (const float*)d_in[2];
    const float* b1 = (const float*)d_in[3];
    const float* W2 = (const float*)d_in[4];
    const float* b2 = (const float*)d_in[5];

    char* ws = (char*)d_ws;
    unsigned short* Wt1 = (unsigned short*)(ws);
    unsigned short* Wt2 = (unsigned short*)(ws + 65536);
    unsigned short* xb  = (unsigned short*)(ws + 131072);              // N x D bf16
    unsigned short* h1  = (unsigned short*)(ws + 131072 + 12800000);   // N x D bf16

    prep<<<128 + 6250, 256, 0, stream>>>(x, xb, W1, W2, Wt1, Wt2);

    const int mgrid = (N_NODES + BM - 1) / BM;  // 782
    sage_layer<1><<<mgrid, 256, 0, stream>>>(xb, nb, Wt1, b1, h1);
    sage_layer<0><<<mgrid, 256, 0, stream>>>(h1, nb, Wt2, b2, d_out);
}

// Round 3
// 153.710 us; speedup vs baseline: 1.3010x; 1.3010x over previous
//
#include <hip/hip_runtime.h>
#include <hip/hip_bf16.h>

// GraphSAGE 2-layer: N=50000, D=128, DEG=16.
// R3: fused gather+GEMM, BM=32 (1563 blocks), 16-deep neighbor-load pipelining,
//     __launch_bounds__(256,4) for 4 blocks/CU. 3 launches.
typedef __attribute__((ext_vector_type(8))) short short8;
typedef __attribute__((ext_vector_type(4))) float f32x4;

#define N_NODES 50000
#define D 128
#define DEG 16
#define K2 256   // 2*D
#define BM 32    // rows per block

static __device__ __forceinline__ unsigned short f2b(float f) {
    union { float f; unsigned int u; } v; v.f = f;
    return (unsigned short)((v.u + 0x7fffu + ((v.u >> 16) & 1u)) >> 16);
}
static __device__ __forceinline__ float b2f(unsigned short u) {
    union { unsigned int u; float f; } v; v.u = ((unsigned int)u) << 16;
    return v.f;
}

// ---- prep: x -> bf16 ; W1,W2 -> bf16 transposed (n-major) ----
__global__ void prep(const float* __restrict__ x, unsigned short* __restrict__ xb,
                     const float* __restrict__ W1, const float* __restrict__ W2,
                     unsigned short* __restrict__ Wt1, unsigned short* __restrict__ Wt2) {
    int b = blockIdx.x;
    if (b < 128) {
        int i = b * 256 + threadIdx.x;       // i in [0, K2*D)
        int k = i / D, n = i % D;
        Wt1[n * K2 + k] = f2b(W1[i]);
        Wt2[n * K2 + k] = f2b(W2[i]);
    } else {
        int i = ((b - 128) * 256 + threadIdx.x) * 4;
        if (i < N_NODES * D) {
            float4 v = *(const float4*)(x + i);
            ushort4 o;
            o.x = f2b(v.x); o.y = f2b(v.y); o.z = f2b(v.z); o.w = f2b(v.w);
            *(ushort4*)(xb + i) = o;
        }
    }
}

// ---- fused layer: out = relu( [feat | mean_nbr(feat)] @ W + b ) ----
template <int OUT_BF16>
__global__ __launch_bounds__(256, 4)
void sage_layer(const unsigned short* __restrict__ feat,  // N x D bf16
                const int* __restrict__ nbr,              // N x DEG
                const unsigned short* __restrict__ wt,    // D x K2 bf16 (n-major)
                const float* __restrict__ bias,           // D f32
                void* __restrict__ out)
{
    __shared__ __align__(16) unsigned short Hl[BM * 264];  // A tile, row stride 264
    __shared__ int Nl[BM * DEG];                           // 512 neighbor ids
    const int tid  = threadIdx.x;
    const int row0 = blockIdx.x * BM;

    // stage neighbor indices (512 ints)
    if (tid < 128) {
        int g = row0 * DEG + tid * 4;
        int gmax = N_NODES * DEG - 4;
        if (g > gmax) g = gmax;              // tail clamp; extra rows unused
        *(int4*)(Nl + tid * 4) = *(const int4*)(nbr + g);
    }
    __syncthreads();

    // ---- gather: 2 (row, 8-dim-slice) pairs per thread; 16 loads in flight each
    #pragma unroll
    for (int p = 0; p < 2; ++p) {
        int a = tid + p * 256;
        int r = a >> 4;                      // 0..31
        int s = a & 15;                      // 8-dim slice
        int grow = row0 + r;
        if (grow >= N_NODES) grow = N_NODES - 1;
        const unsigned short* sp = feat + (size_t)grow * D + s * 8;
        short8 self = *(const short8*)sp;

        int4 i0 = *(const int4*)(Nl + r * 16);
        int4 i1 = *(const int4*)(Nl + r * 16 + 4);
        int4 i2 = *(const int4*)(Nl + r * 16 + 8);
        int4 i3 = *(const int4*)(Nl + r * 16 + 12);
        int ids[16] = { i0.x, i0.y, i0.z, i0.w, i1.x, i1.y, i1.z, i1.w,
                        i2.x, i2.y, i2.z, i2.w, i3.x, i3.y, i3.z, i3.w };

        short8 v[16];
        #pragma unroll
        for (int j = 0; j < 16; ++j)
            v[j] = *(const short8*)(feat + (size_t)ids[j] * D + s * 8);

        float am[8];
        #pragma unroll
        for (int i = 0; i < 8; ++i) am[i] = 0.f;
        #pragma unroll
        for (int j = 0; j < 16; ++j)
            #pragma unroll
            for (int i = 0; i < 8; ++i)
                am[i] += b2f((unsigned short)v[j][i]);

        unsigned short* hr = Hl + r * 264 + s * 8;
        *(short8*)(hr) = self;
        short8 m;
        #pragma unroll
        for (int i = 0; i < 8; ++i) m[i] = (short)f2b(am[i] * 0.0625f);
        *(short8*)(hr + D) = m;
    }

    // ---- B fragments
    const int lane = tid & 63;
    const int w    = tid >> 6;
    const int quad = lane >> 4;
    const int l16  = lane & 15;
    const int n_base = w * 32;
    short8 bfrag[8][2];
    #pragma unroll
    for (int kk = 0; kk < 8; ++kk)
        #pragma unroll
        for (int ct = 0; ct < 2; ++ct)
            bfrag[kk][ct] = *(const short8*)(wt + (n_base + ct * 16 + l16) * K2 + kk * 32 + quad * 8);

    __syncthreads();

    // ---- MFMA: 32 rows (2 rt) x 32 cols (2 ct) per wave
    f32x4 acc[2][2];
    #pragma unroll
    for (int rt = 0; rt < 2; ++rt)
        #pragma unroll
        for (int ct = 0; ct < 2; ++ct)
            acc[rt][ct] = (f32x4){0.f, 0.f, 0.f, 0.f};

    #pragma unroll
    for (int kk = 0; kk < 8; ++kk) {
        short8 afrag[2];
        #pragma unroll
        for (int rt = 0; rt < 2; ++rt)
            afrag[rt] = *(const short8*)(&Hl[(rt * 16 + l16) * 264 + kk * 32 + quad * 8]);
        #pragma unroll
        for (int rt = 0; rt < 2; ++rt)
            #pragma unroll
            for (int ct = 0; ct < 2; ++ct)
                acc[rt][ct] = __builtin_amdgcn_mfma_f32_16x16x32_bf16(
                    afrag[rt], bfrag[kk][ct], acc[rt][ct], 0, 0, 0);
    }

    // ---- epilogue
    float bv0 = bias[n_base + l16];
    float bv1 = bias[n_base + 16 + l16];
    #pragma unroll
    for (int rt = 0; rt < 2; ++rt) {
        int grow_base = row0 + rt * 16 + quad * 4;
        #pragma unroll
        for (int r = 0; r < 4; ++r) {
            int grow = grow_base + r;
            if (grow >= N_NODES) continue;
            #pragma unroll
            for (int ct = 0; ct < 2; ++ct) {
                float vv = acc[rt][ct][r] + (ct ? bv1 : bv0);
                vv = vv > 0.f ? vv : 0.f;
                int col = n_base + ct * 16 + l16;
                if (OUT_BF16)
                    ((unsigned short*)out)[grow * D + col] = f2b(vv);
                else
                    ((float*)out)[grow * D + col] = vv;
            }
        }
    }
}

extern "C" void kernel_launch(void* const* d_in, const int* in_sizes, int n_in,
                              void* d_out, int out_size, void* d_ws, size_t ws_size,
                              hipStream_t stream) {
    const float* x  = (const float*)d_in[0];
    const int*   nb = (const int*)d_in[1];
    const float* W1 = (const float*)d_in[2];
    const float* b1 = (const float*)d_in[3];
    const float* W2 = (const float*)d_in[4];
    const float* b2 = (const float*)d_in[5];

    char* ws = (char*)d_ws;
    unsigned short* Wt1 = (unsigned short*)(ws);
    unsigned short* Wt2 = (unsigned short*)(ws + 65536);
    unsigned short* xb  = (unsigned short*)(ws + 131072);              // N x D bf16
    unsigned short* h1  = (unsigned short*)(ws + 131072 + 12800000);   // N x D bf16

    prep<<<128 + 6250, 256, 0, stream>>>(x, xb, W1, W2, Wt1, Wt2);

    const int mgrid = (N_NODES + BM - 1) / BM;  // 1563
    sage_layer<1><<<mgrid, 256, 0, stream>>>(xb, nb, Wt1, b1, h1);
    sage_layer<0><<<mgrid, 256, 0, stream>>>(h1, nb, Wt2, b2, d_out);
}